// Round 1
// 751.405 us; speedup vs baseline: 1.0356x; 1.0356x over previous
//
#include <hip/hip_runtime.h>
#include <hip/hip_fp16.h>
#include <math.h>

// ---------------------------------------------------------------------------
// EdgeGAT R8: aggregation gather restructure.
//  - agg_bn: 32 lanes x uint4 per h-row -> 2 edges per load instruction
//    (wave halves own alternating edges), 8-edge unroll, 32-bit gather
//    offsets, halved redundant softmax work. Cross-half shfl_xor combine
//    once per node.
//  - agg3: 8 lanes x uint4 per 128B row -> 8 edges in flight (was 4),
//    halved load instructions.
//  - Everything else (CSR build, MFMA GEMM + fused attn/BN, edge_out)
//    unchanged from R7.
// ---------------------------------------------------------------------------

#define FIN 128
#define HID 64
#define BIN_SHIFT 8   // 256 nodes per bin; requires N <= 65536

typedef _Float16 f16x8 __attribute__((ext_vector_type(8)));
typedef float f32x4 __attribute__((ext_vector_type(4)));

__device__ __forceinline__ unsigned short f2hbits(float f) {
    __half h = __float2half(f);
    return *reinterpret_cast<unsigned short*>(&h);
}
__device__ __forceinline__ float2 hpair(unsigned w) {
    __half2 h = *reinterpret_cast<__half2*>(&w);
    return __half22float2(h);
}

// monotone float<->uint encoding for atomicMax on floats
__device__ __forceinline__ unsigned fenc(float f) {
    unsigned b = __float_as_uint(f);
    return (b & 0x80000000u) ? ~b : (b | 0x80000000u);
}
__device__ __forceinline__ float fdec(unsigned k) {
    unsigned b = (k & 0x80000000u) ? (k ^ 0x80000000u) : ~k;
    return __uint_as_float(b);
}

// ---------------- binned CSR build ----------------

__global__ __launch_bounds__(256) void bincount_kernel(const int* __restrict__ ei,
                                                       int* __restrict__ bincnt,
                                                       int E, int Etot) {
    __shared__ int h[256];
    int t = threadIdx.x;
    h[t] = 0;
    __syncthreads();
    int base = blockIdx.x * 4096;
    #pragma unroll
    for (int i = 0; i < 16; ++i) {
        int e = base + i * 256 + t;
        if (e < Etot) {
            int d = (e < E) ? ei[E + e] : (e - E);
            atomicAdd(&h[d >> BIN_SHIFT], 1);
        }
    }
    __syncthreads();
    if (h[t]) atomicAdd(&bincnt[t], h[t]);
}

__global__ void scanbins_kernel(const int* __restrict__ bincnt, int* __restrict__ binptr,
                                int* __restrict__ bincur, int NB, int Etot) {
    __shared__ int buf[256];
    int t = threadIdx.x;  // 256
    int v = (t < NB) ? bincnt[t] : 0;
    buf[t] = v;
    __syncthreads();
    for (int o = 1; o < 256; o <<= 1) {
        int y = (t >= o) ? buf[t - o] : 0;
        __syncthreads();
        buf[t] += y;
        __syncthreads();
    }
    int excl = buf[t] - v;
    if (t < NB) {
        binptr[t] = excl;
        bincur[t] = excl;
    }
    if (t == 0) binptr[NB] = Etot;
}

__global__ __launch_bounds__(256) void binscatter_kernel(const int* __restrict__ ei,
                                                         int* __restrict__ bincur,
                                                         int2* __restrict__ binned,
                                                         int E, int Etot) {
    __shared__ int h[256];
    __shared__ int gb[256];
    int t = threadIdx.x;
    h[t] = 0;
    __syncthreads();
    int base = blockIdx.x * 4096;
    #pragma unroll
    for (int i = 0; i < 16; ++i) {
        int e = base + i * 256 + t;
        if (e < Etot) {
            int d = (e < E) ? ei[E + e] : (e - E);
            atomicAdd(&h[d >> BIN_SHIFT], 1);
        }
    }
    __syncthreads();
    int cnt = h[t];
    if (cnt) gb[t] = atomicAdd(&bincur[t], cnt);
    __syncthreads();
    h[t] = 0;
    __syncthreads();
    #pragma unroll
    for (int i = 0; i < 16; ++i) {
        int e = base + i * 256 + t;
        if (e < Etot) {
            int s, d;
            if (e < E) { s = ei[e]; d = ei[E + e]; }
            else       { s = e - E; d = e - E; }
            int b = d >> BIN_SHIFT;
            int pos = gb[b] + atomicAdd(&h[b], 1);
            binned[pos] = make_int2(s, d);
        }
    }
}

__global__ __launch_bounds__(256) void bincsr_kernel(const int2* __restrict__ binned,
                                                     const int* __restrict__ binptr,
                                                     int* __restrict__ row_ptr,
                                                     int* __restrict__ col,
                                                     int N, int Etot) {
    __shared__ int h[256];
    __shared__ int cur[256];
    __shared__ int wsum[4];
    int b = blockIdx.x;
    int t = threadIdx.x;
    int lo = b << BIN_SHIFT;
    h[t] = 0;
    __syncthreads();
    int ebeg = binptr[b], eend = binptr[b + 1];
    for (int i = ebeg + t; i < eend; i += 256) atomicAdd(&h[binned[i].y - lo], 1);
    __syncthreads();
    int v = h[t];
    int lane = t & 63, w = t >> 6;
    int x = v;
    #pragma unroll
    for (int o = 1; o < 64; o <<= 1) {
        int y = __shfl_up(x, o);
        if (lane >= o) x += y;
    }
    if (lane == 63) wsum[w] = x;
    __syncthreads();
    int off = 0;
    #pragma unroll
    for (int i = 0; i < 4; ++i) off += (i < w) ? wsum[i] : 0;
    int excl = ebeg + off + x - v;
    int node = lo + t;
    if (node < N) row_ptr[node] = excl;
    cur[t] = excl;
    if (b == 0 && t == 0) row_ptr[N] = Etot;
    __syncthreads();
    for (int i = ebeg + t; i < eend; i += 256) {
        int2 sd = binned[i];
        int pos = atomicAdd(&cur[sd.y - lo], 1);
        col[pos] = sd.x;
    }
}

// ---------------- MFMA GEMM (f16) + fused BN-from-sums + fused attn ---------

__global__ __launch_bounds__(256) void mfma_gemm_kernel(
    const float* __restrict__ X, const float* __restrict__ W,
    unsigned short* __restrict__ Yh, int Nrows, int K, int M,
    const float* __restrict__ bnsum, const float* __restrict__ bng,
    const float* __restrict__ bnb, float invN,
    const float* __restrict__ as_, const float* __restrict__ ad_,
    float* __restrict__ ls, float* __restrict__ ld,
    unsigned* __restrict__ lsmax_g, int H) {
    __shared__ __align__(16) unsigned short a_lds[128][40];
    __shared__ __align__(16) unsigned short b_lds[64][40];
    __shared__ __align__(16) float scale_l[256];
    __shared__ __align__(16) float shift_l[256];
    __shared__ unsigned lmax_l;
    const int t = threadIdx.x;
    const int row0 = blockIdx.x * 128;
    const int by = blockIdx.y;
    const int c0 = by * 64;
    const int w = t >> 6, lane = t & 63;
    const int quad = lane >> 4, mrow = lane & 15;
    if (t == 0) lmax_l = 0;
    if (bnsum && t < 256) {
        float mu = bnsum[t] * invN;
        float var = bnsum[256 + t] * invN - mu * mu;
        float sc = bng[t] * rsqrtf(var + 1e-5f);
        scale_l[t] = sc;
        shift_l[t] = bnb[t] - mu * sc;
    }
    __syncthreads();
    f32x4 acc[2][4] = {};
    for (int k0 = 0; k0 < K; k0 += 32) {
        #pragma unroll
        for (int i = 0; i < 4; ++i) {
            int f = i * 256 + t;
            int r = f >> 3, kq = f & 7;
            int grow = row0 + r;
            float4 xv = make_float4(0.f, 0.f, 0.f, 0.f);
            if (grow < Nrows) xv = *(const float4*)(X + (size_t)grow * K + k0 + kq * 4);
            if (bnsum) {
                float4 sc = *(const float4*)&scale_l[k0 + kq * 4];
                float4 sh = *(const float4*)&shift_l[k0 + kq * 4];
                xv.x = fmaf(xv.x, sc.x, sh.x);
                xv.y = fmaf(xv.y, sc.y, sh.y);
                xv.z = fmaf(xv.z, sc.z, sh.z);
                xv.w = fmaf(xv.w, sc.w, sh.w);
            }
            ushort4 pk;
            pk.x = f2hbits(xv.x);
            pk.y = f2hbits(xv.y);
            pk.z = f2hbits(xv.z);
            pk.w = f2hbits(xv.w);
            *(ushort4*)&a_lds[r][kq * 4] = pk;
        }
        #pragma unroll
        for (int i = 0; i < 2; ++i) {
            int f = i * 256 + t;
            int kr = f >> 4, cq = f & 15;
            float4 wv = *(const float4*)(W + (size_t)(k0 + kr) * M + c0 + cq * 4);
            b_lds[cq * 4 + 0][kr] = f2hbits(wv.x);
            b_lds[cq * 4 + 1][kr] = f2hbits(wv.y);
            b_lds[cq * 4 + 2][kr] = f2hbits(wv.z);
            b_lds[cq * 4 + 3][kr] = f2hbits(wv.w);
        }
        __syncthreads();
        f16x8 a0 = *(const f16x8*)&a_lds[w * 32 + mrow][quad * 8];
        f16x8 a1 = *(const f16x8*)&a_lds[w * 32 + 16 + mrow][quad * 8];
        #pragma unroll
        for (int c = 0; c < 4; ++c) {
            f16x8 bf = *(const f16x8*)&b_lds[c * 16 + mrow][quad * 8];
            acc[0][c] = __builtin_amdgcn_mfma_f32_16x16x32_f16(a0, bf, acc[0][c], 0, 0, 0);
            acc[1][c] = __builtin_amdgcn_mfma_f32_16x16x32_f16(a1, bf, acc[1][c], 0, 0, 0);
        }
        __syncthreads();
    }
    // C/D: col = c*16+mrow, row = w*32 + i*16 + quad*4 + r
    #pragma unroll
    for (int i = 0; i < 2; ++i) {
        #pragma unroll
        for (int c = 0; c < 4; ++c) {
            #pragma unroll
            for (int r = 0; r < 4; ++r) {
                int grow = row0 + w * 32 + i * 16 + quad * 4 + r;
                if (grow < Nrows)
                    Yh[(size_t)grow * M + c0 + c * 16 + mrow] = f2hbits(acc[i][c][r]);
            }
        }
    }
    // fused attn: ls/ld for this head's 64 cols
    float asv[4], adv[4];
    #pragma unroll
    for (int c = 0; c < 4; ++c) {
        asv[c] = as_[by * 64 + c * 16 + mrow];
        adv[c] = ad_[by * 64 + c * 16 + mrow];
    }
    float lmax = -3.0e38f;
    #pragma unroll
    for (int i = 0; i < 2; ++i) {
        #pragma unroll
        for (int r = 0; r < 4; ++r) {
            float ps = 0.f, pd = 0.f;
            #pragma unroll
            for (int c = 0; c < 4; ++c) {
                ps = fmaf(acc[i][c][r], asv[c], ps);
                pd = fmaf(acc[i][c][r], adv[c], pd);
            }
            #pragma unroll
            for (int o = 1; o <= 8; o <<= 1) {
                ps += __shfl_xor(ps, o);
                pd += __shfl_xor(pd, o);
            }
            int grow = row0 + w * 32 + i * 16 + quad * 4 + r;
            if (mrow == 0 && grow < Nrows) {
                ls[(size_t)grow * H + by] = ps;
                ld[(size_t)grow * H + by] = pd;
                lmax = fmaxf(lmax, ps);
            }
        }
    }
    if (mrow == 0) atomicMax(&lmax_l, fenc(lmax));
    __syncthreads();
    if (t == 0) atomicMax(&lsmax_g[by], lmax_l);
}

// ---------------- layers 1/2 aggregation + fused BN stats -------------------
// One wave per node. 32 lanes x uint4 cover the 512B h-row -> the two wave
// halves process 2 edges per load instruction; 8-edge unroll keeps
// 4 dwordx4 + 4 ls gathers in flight. 32-bit byte offsets for gathers.

#define ACC8(hv, p)                                              \
    {                                                            \
        float2 fa = hpair((hv).x), fb = hpair((hv).y);           \
        float2 fc = hpair((hv).z), fd = hpair((hv).w);           \
        a0 = fmaf((p), fa.x, a0); a1 = fmaf((p), fa.y, a1);      \
        a2 = fmaf((p), fb.x, a2); a3 = fmaf((p), fb.y, a3);      \
        a4 = fmaf((p), fc.x, a4); a5 = fmaf((p), fc.y, a5);      \
        a6 = fmaf((p), fd.x, a6); a7 = fmaf((p), fd.y, a7);      \
    }

__global__ __launch_bounds__(256) void agg_bn_kernel(
    const unsigned short* __restrict__ hb, const float* __restrict__ ls,
    const float* __restrict__ ld, const int* __restrict__ row_ptr,
    const int* __restrict__ col, const float* __restrict__ bias,
    const unsigned* __restrict__ lsmax_g, float* __restrict__ out,
    float* __restrict__ bnsum, int N, int ngroups) {
    __shared__ float accs[4][256];
    __shared__ float accq[4][256];
    const int t = threadIdx.x;
    const int w = t >> 6, lane = t & 63;
    const int half = lane >> 5;        // which edge of the pair
    const int il = lane & 31;          // 32 lanes cover 256 channels
    const int hd = il >> 3;            // head 0..3
    const int c0 = il * 8;             // 8 channels per lane
    const char* hbb = (const char*)hb;
    const char* lsc = (const char*)ls;
    const unsigned cb = (unsigned)c0 * 2u;
    const unsigned hd4 = (unsigned)hd * 4u;
    if (half == 0) {
        #pragma unroll
        for (int i = 0; i < 8; ++i) { accs[w][c0 + i] = 0.f; accq[w][c0 + i] = 0.f; }
    }
    const float lsm = fdec(lsmax_g[hd]);
    const float4 bv0 = *(const float4*)(bias + c0);
    const float4 bv1 = *(const float4*)(bias + c0 + 4);
    for (int g = blockIdx.x; g < ngroups; g += gridDim.x) {
        int n = g * 4 + w;
        if (n >= N) continue;
        int beg = row_ptr[n], end = row_ptr[n + 1];
        float4 ldn = *(const float4*)(ld + (size_t)n * 4);
        float ldn_h = (hd == 0) ? ldn.x : (hd == 1) ? ldn.y : (hd == 2) ? ldn.z : ldn.w;
        float m_h = fmaxf(0.f, ldn_h + lsm);
        float psum = 0.f;
        float a0 = 0.f, a1 = 0.f, a2 = 0.f, a3 = 0.f;
        float a4 = 0.f, a5 = 0.f, a6 = 0.f, a7 = 0.f;
        for (int base = beg; base < end; base += 64) {
            int el = base + lane;
            int s_r = (el < end) ? col[el] : 0;
            int cnt = min(64, end - base);
            int j = 0;
            for (; j + 8 <= cnt; j += 8) {
                int s0 = __shfl(s_r, j + half);
                int s1 = __shfl(s_r, j + 2 + half);
                int s2 = __shfl(s_r, j + 4 + half);
                int s3 = __shfl(s_r, j + 6 + half);
                uint4 h0 = *(const uint4*)(hbb + ((unsigned)s0 * 512u + cb));
                uint4 h1 = *(const uint4*)(hbb + ((unsigned)s1 * 512u + cb));
                uint4 h2 = *(const uint4*)(hbb + ((unsigned)s2 * 512u + cb));
                uint4 h3 = *(const uint4*)(hbb + ((unsigned)s3 * 512u + cb));
                float l0 = *(const float*)(lsc + ((unsigned)s0 * 16u + hd4));
                float l1 = *(const float*)(lsc + ((unsigned)s1 * 16u + hd4));
                float l2 = *(const float*)(lsc + ((unsigned)s2 * 16u + hd4));
                float l3 = *(const float*)(lsc + ((unsigned)s3 * 16u + hd4));
                float g0 = l0 + ldn_h; g0 = fmaxf(g0, 0.2f * g0);
                float g1 = l1 + ldn_h; g1 = fmaxf(g1, 0.2f * g1);
                float g2 = l2 + ldn_h; g2 = fmaxf(g2, 0.2f * g2);
                float g3 = l3 + ldn_h; g3 = fmaxf(g3, 0.2f * g3);
                float p0 = __expf(g0 - m_h), p1 = __expf(g1 - m_h);
                float p2 = __expf(g2 - m_h), p3 = __expf(g3 - m_h);
                psum += (p0 + p1) + (p2 + p3);
                ACC8(h0, p0) ACC8(h1, p1) ACC8(h2, p2) ACC8(h3, p3)
            }
            for (; j < cnt; j += 2) {
                int jj = j + half;                 // jj <= cnt <= 63 here
                int sj = __shfl(s_r, jj);          // lane cnt..63 hold s=0 (safe)
                bool valid = jj < cnt;
                uint4 hv = *(const uint4*)(hbb + ((unsigned)sj * 512u + cb));
                float lv = *(const float*)(lsc + ((unsigned)sj * 16u + hd4));
                float gg = lv + ldn_h; gg = fmaxf(gg, 0.2f * gg);
                float pv = valid ? __expf(gg - m_h) : 0.f;
                psum += pv;
                ACC8(hv, pv)
            }
        }
        // combine the two halves (each processed alternating edges)
        psum += __shfl_xor(psum, 32);
        a0 += __shfl_xor(a0, 32); a1 += __shfl_xor(a1, 32);
        a2 += __shfl_xor(a2, 32); a3 += __shfl_xor(a3, 32);
        a4 += __shfl_xor(a4, 32); a5 += __shfl_xor(a5, 32);
        a6 += __shfl_xor(a6, 32); a7 += __shfl_xor(a7, 32);
        if (half == 0) {
            float inv = 1.f / (psum + 1e-16f);
            float o0 = fmaf(a0, inv, bv0.x);
            float o1 = fmaf(a1, inv, bv0.y);
            float o2 = fmaf(a2, inv, bv0.z);
            float o3 = fmaf(a3, inv, bv0.w);
            float o4 = fmaf(a4, inv, bv1.x);
            float o5 = fmaf(a5, inv, bv1.y);
            float o6 = fmaf(a6, inv, bv1.z);
            float o7 = fmaf(a7, inv, bv1.w);
            o0 = (o0 > 0.f) ? o0 : expm1f(o0);
            o1 = (o1 > 0.f) ? o1 : expm1f(o1);
            o2 = (o2 > 0.f) ? o2 : expm1f(o2);
            o3 = (o3 > 0.f) ? o3 : expm1f(o3);
            o4 = (o4 > 0.f) ? o4 : expm1f(o4);
            o5 = (o5 > 0.f) ? o5 : expm1f(o5);
            o6 = (o6 > 0.f) ? o6 : expm1f(o6);
            o7 = (o7 > 0.f) ? o7 : expm1f(o7);
            float* orow = out + (size_t)n * 256 + c0;
            *(float4*)orow = make_float4(o0, o1, o2, o3);
            *(float4*)(orow + 4) = make_float4(o4, o5, o6, o7);
            accs[w][c0 + 0] += o0; accq[w][c0 + 0] += o0 * o0;
            accs[w][c0 + 1] += o1; accq[w][c0 + 1] += o1 * o1;
            accs[w][c0 + 2] += o2; accq[w][c0 + 2] += o2 * o2;
            accs[w][c0 + 3] += o3; accq[w][c0 + 3] += o3 * o3;
            accs[w][c0 + 4] += o4; accq[w][c0 + 4] += o4 * o4;
            accs[w][c0 + 5] += o5; accq[w][c0 + 5] += o5 * o5;
            accs[w][c0 + 6] += o6; accq[w][c0 + 6] += o6 * o6;
            accs[w][c0 + 7] += o7; accq[w][c0 + 7] += o7 * o7;
        }
    }
    __syncthreads();
    float s = accs[0][t] + accs[1][t] + accs[2][t] + accs[3][t];
    float q = accq[0][t] + accq[1][t] + accq[2][t] + accq[3][t];
    atomicAdd(&bnsum[t], s);
    atomicAdd(&bnsum[256 + t], q);
}

// ---------------- layer-3 aggregation (H=1): 8 edges in flight --------------

__global__ __launch_bounds__(256) void agg3_kernel(
    const unsigned short* __restrict__ hb, const float* __restrict__ ls,
    const float* __restrict__ ld, const int* __restrict__ row_ptr,
    const int* __restrict__ col, const float* __restrict__ bias,
    const float* __restrict__ fcW, float* __restrict__ up, float* __restrict__ vp,
    const unsigned* __restrict__ lsmax_g, int N) {
    int lane = threadIdx.x & 63;
    int n = blockIdx.x * 4 + (threadIdx.x >> 6);
    if (n >= N) return;
    int beg = row_ptr[n], end = row_ptr[n + 1];
    float ldn = ld[n];
    float m_h = fmaxf(0.f, ldn + fdec(lsmax_g[0]));
    int g = lane >> 3;    // edge group 0..7
    int li = lane & 7;    // channel octet 0..7
    int c0 = li * 8;
    const char* hbb = (const char*)hb;
    const unsigned cb = (unsigned)c0 * 2u;
    float psum = 0.f;
    float a0 = 0.f, a1 = 0.f, a2 = 0.f, a3 = 0.f;
    float a4 = 0.f, a5 = 0.f, a6 = 0.f, a7 = 0.f;
    for (int j = beg + g; j < end; j += 8) {
        int s = col[j];
        uint4 hv = *(const uint4*)(hbb + ((unsigned)s * 128u + cb));
        float lg = ls[s] + ldn;
        lg = fmaxf(lg, 0.2f * lg);
        float pv = __expf(lg - m_h);
        psum += pv;
        ACC8(hv, pv)
    }
    #pragma unroll
    for (int o = 8; o <= 32; o <<= 1) {
        psum += __shfl_xor(psum, o);
        a0 += __shfl_xor(a0, o); a1 += __shfl_xor(a1, o);
        a2 += __shfl_xor(a2, o); a3 += __shfl_xor(a3, o);
        a4 += __shfl_xor(a4, o); a5 += __shfl_xor(a5, o);
        a6 += __shfl_xor(a6, o); a7 += __shfl_xor(a7, o);
    }
    float inv = 1.f / (psum + 1e-16f);
    float v0 = fmaf(a0, inv, bias[c0 + 0]);
    float v1 = fmaf(a1, inv, bias[c0 + 1]);
    float v2 = fmaf(a2, inv, bias[c0 + 2]);
    float v3 = fmaf(a3, inv, bias[c0 + 3]);
    float v4 = fmaf(a4, inv, bias[c0 + 4]);
    float v5 = fmaf(a5, inv, bias[c0 + 5]);
    float v6 = fmaf(a6, inv, bias[c0 + 6]);
    float v7 = fmaf(a7, inv, bias[c0 + 7]);
    float pu = v0 * fcW[c0] + v1 * fcW[c0 + 1] + v2 * fcW[c0 + 2] + v3 * fcW[c0 + 3] +
               v4 * fcW[c0 + 4] + v5 * fcW[c0 + 5] + v6 * fcW[c0 + 6] + v7 * fcW[c0 + 7];
    float pv2 = v0 * fcW[64 + c0] + v1 * fcW[64 + c0 + 1] + v2 * fcW[64 + c0 + 2] +
                v3 * fcW[64 + c0 + 3] + v4 * fcW[64 + c0 + 4] + v5 * fcW[64 + c0 + 5] +
                v6 * fcW[64 + c0 + 6] + v7 * fcW[64 + c0 + 7];
    #pragma unroll
    for (int o = 1; o <= 4; o <<= 1) {
        pu += __shfl_xor(pu, o);
        pv2 += __shfl_xor(pv2, o);
    }
    if (lane == 0) {
        up[n] = pu;
        vp[n] = pv2;
    }
}

// ---------------- final edge output (prep folded in) ------------------------

__global__ __launch_bounds__(256) void edge_out_kernel(
    const int* __restrict__ ei, const float* __restrict__ ea,
    const float* __restrict__ W1, const float* __restrict__ b1,
    const float* __restrict__ mlpW2, const float* __restrict__ mlpb2,
    const float* __restrict__ fcW, const float* __restrict__ fcb,
    const float* __restrict__ u, const float* __restrict__ v,
    float* __restrict__ out, int E) {
    __shared__ __align__(16) float W1T[64][16];
    __shared__ float w2fl[64];
    __shared__ float b1l[64];
    __shared__ float c2l;
    int t = threadIdx.x;
    for (int p = t; p < 1024; p += 256) {
        int i = p >> 6, j = p & 63;
        W1T[j][i] = W1[i * 64 + j];
    }
    if (t < 64) {
        float s = 0.f;
        for (int k = 0; k < 64; ++k) s = fmaf(mlpW2[t * 64 + k], fcW[128 + k], s);
        w2fl[t] = s;
        b1l[t] = b1[t];
    }
    if (t == 0) {
        float c = fcb[0];
        for (int k = 0; k < 64; ++k) c = fmaf(mlpb2[k], fcW[128 + k], c);
        c2l = c;
    }
    __syncthreads();
    int base = blockIdx.x * 1024;
    float eav[4][16];
    int sidx[4], didx[4];
    bool ok[4];
    #pragma unroll
    for (int k = 0; k < 4; ++k) {
        int e = base + k * 256 + t;
        ok[k] = e < E;
        int ec = ok[k] ? e : 0;
        sidx[k] = ei[ec];
        didx[k] = ei[E + ec];
        const float4* ear = (const float4*)(ea + (size_t)ec * 16);
        float4 q0 = ear[0], q1 = ear[1], q2 = ear[2], q3 = ear[3];
        eav[k][0] = q0.x;  eav[k][1] = q0.y;  eav[k][2] = q0.z;  eav[k][3] = q0.w;
        eav[k][4] = q1.x;  eav[k][5] = q1.y;  eav[k][6] = q1.z;  eav[k][7] = q1.w;
        eav[k][8] = q2.x;  eav[k][9] = q2.y;  eav[k][10] = q2.z; eav[k][11] = q2.w;
        eav[k][12] = q3.x; eav[k][13] = q3.y; eav[k][14] = q3.z; eav[k][15] = q3.w;
    }
    float acc[4] = {0.f, 0.f, 0.f, 0.f};
    #pragma unroll 4
    for (int j = 0; j < 64; ++j) {
        const float4* wr = (const float4*)&W1T[j][0];
        float4 w0 = wr[0], w1 = wr[1], w2 = wr[2], w3 = wr[3];
        float wrow[16] = {w0.x, w0.y, w0.z, w0.w, w1.x, w1.y, w1.z, w1.w,
                          w2.x, w2.y, w2.z, w2.w, w3.x, w3.y, w3.z, w3.w};
        float bj = b1l[j], wj = w2fl[j];
        #pragma unroll
        for (int k = 0; k < 4; ++k) {
            float s = bj;
            #pragma unroll
            for (int q = 0; q < 16; ++q) s = fmaf(eav[k][q], wrow[q], s);
            s = fmaxf(s, 0.f);
            acc[k] = fmaf(s, wj, acc[k]);
        }
    }
    float cc = c2l;
    #pragma unroll
    for (int k = 0; k < 4; ++k) {
        if (ok[k]) {
            int e = base + k * 256 + t;
            out[e] = u[sidx[k]] + v[didx[k]] + acc[k] + cc;
        }
    }
}

// ---------------- orchestration ----------------

extern "C" void kernel_launch(void* const* d_in, const int* in_sizes, int n_in,
                              void* d_out, int out_size, void* d_ws, size_t ws_size,
                              hipStream_t stream) {
    const float* x     = (const float*)d_in[0];
    const int*   ei    = (const int*)d_in[1];
    const float* ea    = (const float*)d_in[2];
    const float* W1    = (const float*)d_in[3];
    const float* a1s   = (const float*)d_in[4];
    const float* a1d   = (const float*)d_in[5];
    const float* b1    = (const float*)d_in[6];
    const float* W2    = (const float*)d_in[7];
    const float* a2s   = (const float*)d_in[8];
    const float* a2d   = (const float*)d_in[9];
    const float* b2    = (const float*)d_in[10];
    const float* W3    = (const float*)d_in[11];
    const float* a3s   = (const float*)d_in[12];
    const float* a3d   = (const float*)d_in[13];
    const float* b3    = (const float*)d_in[14];
    const float* bn1g  = (const float*)d_in[15];
    const float* bn1b  = (const float*)d_in[16];
    const float* bn2g  = (const float*)d_in[17];
    const float* bn2b  = (const float*)d_in[18];
    const float* mlpW1 = (const float*)d_in[19];
    const float* mlpb1 = (const float*)d_in[20];
    const float* mlpW2 = (const float*)d_in[21];
    const float* mlpb2 = (const float*)d_in[22];
    const float* fcW   = (const float*)d_in[23];
    const float* fcb   = (const float*)d_in[24];
    float* out = (float*)d_out;

    const int N = in_sizes[0] / FIN;     // 50000
    const int E = in_sizes[1] / 2;       // 1600000
    const int Etot = E + N;
    const int NB = (N + 255) >> BIN_SHIFT;  // 196

    // workspace layout
    char* wsb = (char*)d_ws;
    size_t off = 0;
    auto alloc = [&](size_t bytes) {
        void* p = wsb + off;
        off += (bytes + 63) & ~(size_t)63;
        return p;
    };
    unsigned short* hAb = (unsigned short*)alloc((size_t)N * 256 * 2);  // f16 h
    float* hB  = (float*)alloc((size_t)N * 256 * 4);
    unsigned short* h3b = (unsigned short*)alloc((size_t)N * 64 * 2);   // f16 h3
    float* lsb = (float*)alloc((size_t)N * 4 * 4);
    float* ldb = (float*)alloc((size_t)N * 4 * 4);
    int* row_ptr = (int*)alloc((size_t)(N + 1) * 4);
    int* colb    = (int*)alloc((size_t)Etot * 4);
    int2* binned = (int2*)alloc((size_t)Etot * 8);
    // single contiguous zero-init region:
    // bincnt[256] | lsmax1[4] lsmax2[4] lsmax3[4] pad[4] | bnsumA[512] | bnsumB[512]
    int* zreg    = (int*)alloc((256 + 16 + 512 + 512) * 4);
    int* bincnt  = zreg;
    unsigned* lsmax1 = (unsigned*)(zreg + 256);
    unsigned* lsmax2 = lsmax1 + 4;
    unsigned* lsmax3 = lsmax1 + 8;
    float* bnsumA = (float*)(zreg + 256 + 16);
    float* bnsumB = bnsumA + 512;
    int* binptr  = (int*)alloc((size_t)(NB + 1) * 4);
    int* bincur  = (int*)alloc((size_t)NB * 4);
    float* ub  = (float*)alloc((size_t)N * 4);
    float* vb  = (float*)alloc((size_t)N * 4);
    (void)ws_size; (void)n_in; (void)out_size;

    const int nb4 = (N + 3) / 4;
    const int nch = (Etot + 4095) / 4096;
    const float invN = 1.f / (float)N;

    // ---- CSR build ----
    hipMemsetAsync(zreg, 0, (256 + 16 + 512 + 512) * sizeof(int), stream);
    bincount_kernel<<<nch, 256, 0, stream>>>(ei, bincnt, E, Etot);
    scanbins_kernel<<<1, 256, 0, stream>>>(bincnt, binptr, bincur, NB, Etot);
    binscatter_kernel<<<nch, 256, 0, stream>>>(ei, bincur, binned, E, Etot);
    bincsr_kernel<<<NB, 256, 0, stream>>>(binned, binptr, row_ptr, colb, N, Etot);

    dim3 ggrid((N + 127) / 128, 4);
    dim3 ggrid3((N + 127) / 128, 1);

    // ---- layer 1 ----
    mfma_gemm_kernel<<<ggrid, 256, 0, stream>>>(x, W1, hAb, N, 128, 256,
        nullptr, nullptr, nullptr, invN, a1s, a1d, lsb, ldb, lsmax1, 4);
    agg_bn_kernel<<<2048, 256, 0, stream>>>(hAb, lsb, ldb, row_ptr, colb, b1,
                                            lsmax1, hB, bnsumA, N, nb4);
    // ---- layer 2 ----
    mfma_gemm_kernel<<<ggrid, 256, 0, stream>>>(hB, W2, hAb, N, 256, 256,
        bnsumA, bn1g, bn1b, invN, a2s, a2d, lsb, ldb, lsmax2, 4);
    agg_bn_kernel<<<2048, 256, 0, stream>>>(hAb, lsb, ldb, row_ptr, colb, b2,
                                            lsmax2, hB, bnsumB, N, nb4);
    // ---- layer 3 ----
    mfma_gemm_kernel<<<ggrid3, 256, 0, stream>>>(hB, W3, h3b, N, 256, 64,
        bnsumB, bn2g, bn2b, invN, a3s, a3d, lsb, ldb, lsmax3, 1);
    agg3_kernel<<<nb4, 256, 0, stream>>>(h3b, lsb, ldb, row_ptr, colb, b3,
                                         fcW, ub, vb, lsmax3, N);
    // ---- edge output ----
    edge_out_kernel<<<(E + 1023) / 1024, 256, 0, stream>>>(
        ei, ea, mlpW1, mlpb1, mlpW2, mlpb2, fcW, fcb, ub, vb, out, E);
}